// Round 1
// baseline (1063.756 us; speedup 1.0000x reference)
//
#include <hip/hip_runtime.h>

#define N_PIX 1024      // 32*32 pixels per image
#define BATCH 32
#define CCH 256         // channels == code dim
#define KCODES 4096
#define NROWS 32768     // BATCH * N_PIX

// ---------------- kernel 0: e_sq[k] = sum_c emb[k][c]^2 ----------------
__global__ __launch_bounds__(256) void esq_kernel(const float* __restrict__ emb,
                                                  float* __restrict__ esq) {
    const int t = threadIdx.x;
    const int w = t >> 6, l = t & 63;
    const int k = blockIdx.x * 4 + w;
    const float4 v = *(const float4*)(emb + (size_t)k * CCH + l * 4);
    float s = v.x * v.x + v.y * v.y + v.z * v.z + v.w * v.w;
#pragma unroll
    for (int off = 32; off > 0; off >>= 1) s += __shfl_down(s, off);
    if (l == 0) esq[k] = s;
}

// ---------------- kernel 1: fused distance + argmin ----------------
// block: 256 threads = 4 waves; handles 64 consecutive pixel-rows, loops all codes.
// score(n,k) = esq[k] - 2*dot(x_n, e_k)   (x_sq dropped: constant per row)
__global__ __launch_bounds__(256, 2) void argmin_kernel(
    const float* __restrict__ x, const float* __restrict__ emb,
    const float* __restrict__ esq, int* __restrict__ bidx)
{
    extern __shared__ float lds[];
    float* xs = lds;              // [256][64]  x tile, [c][m]
    float* es = lds + 256 * 64;   // [32][64]   emb chunk, [c_local][k swizzled]

    const int t = threadIdx.x;
    const int n0 = blockIdx.x * 64;
    const int b = n0 >> 10;
    const int pixbase = n0 & (N_PIX - 1);
    const float* xb = x + (size_t)b * CCH * N_PIX + pixbase;

    // stage x tile transposed: xs[c][m] = x[b][c][pixbase+m]; coalesced 256B reads
    {
        const int m4 = (t & 15) * 4;
        const int crow = t >> 4;
#pragma unroll
        for (int p = 0; p < 16; ++p) {
            const int c = p * 16 + crow;
            const float4 v = *(const float4*)(xb + (size_t)c * N_PIX + m4);
            *(float4*)(xs + c * 64 + m4) = v;
        }
    }

    const int tm4 = (t & 15) * 4;   // row group
    const int tk4 = (t >> 4) * 4;   // code group

    float best[4];
    int bk[4];
#pragma unroll
    for (int i = 0; i < 4; ++i) { best[i] = 3.4e38f; bk[i] = 0; }

    for (int kt = 0; kt < KCODES / 64; ++kt) {
        const int k0 = kt * 64;
        float acc[4][4];
#pragma unroll
        for (int i = 0; i < 4; ++i)
#pragma unroll
            for (int j = 0; j < 4; ++j) acc[i][j] = 0.f;

        for (int dc = 0; dc < 8; ++dc) {   // D chunks of 32
            __syncthreads();
            // stage emb chunk transposed+swizzled: es[c][k ^ (((c>>2)&7)<<2)]
            {
                const int c4 = (t & 7) * 4;
#pragma unroll
                for (int kk = 0; kk < 2; ++kk) {
                    const int kl = kk * 32 + (t >> 3);
                    const float4 v = *(const float4*)(emb + (size_t)(k0 + kl) * CCH + dc * 32 + c4);
                    es[(c4 + 0) * 64 + (kl ^ ((((c4 + 0) >> 2) & 7) << 2))] = v.x;
                    es[(c4 + 1) * 64 + (kl ^ ((((c4 + 1) >> 2) & 7) << 2))] = v.y;
                    es[(c4 + 2) * 64 + (kl ^ ((((c4 + 2) >> 2) & 7) << 2))] = v.z;
                    es[(c4 + 3) * 64 + (kl ^ ((((c4 + 3) >> 2) & 7) << 2))] = v.w;
                }
            }
            __syncthreads();
            const float* xsc = xs + dc * 32 * 64;
#pragma unroll 8
            for (int c = 0; c < 32; ++c) {
                const float4 xv = *(const float4*)(xsc + c * 64 + tm4);
                const float4 ev = *(const float4*)(es + c * 64 + (tk4 ^ (((c >> 2) & 7) << 2)));
                const float xr[4] = {xv.x, xv.y, xv.z, xv.w};
                const float er[4] = {ev.x, ev.y, ev.z, ev.w};
#pragma unroll
                for (int i = 0; i < 4; ++i)
#pragma unroll
                    for (int j = 0; j < 4; ++j)
                        acc[i][j] = fmaf(xr[i], er[j], acc[i][j]);
            }
        }
        // running min update (k ascending within thread -> strict < keeps first min)
        const float4 eq = *(const float4*)(esq + k0 + tk4);
        const float eqr[4] = {eq.x, eq.y, eq.z, eq.w};
#pragma unroll
        for (int i = 0; i < 4; ++i) {
#pragma unroll
            for (int j = 0; j < 4; ++j) {
                const float s = fmaf(-2.f, acc[i][j], eqr[j]);
                if (s < best[i]) { best[i] = s; bk[i] = k0 + tk4 + j; }
            }
        }
    }

    // cross-thread reduction: row m = tm4+i is held by 16 threads (tk groups)
    __syncthreads();
    float* rs = es;           // [64][16] scores (8KB region is big enough)
    int* ri = (int*)xs;       // [64][16] indices (reuse xs)
    {
        const int tkq = t >> 4;
#pragma unroll
        for (int i = 0; i < 4; ++i) {
            rs[(tm4 + i) * 16 + tkq] = best[i];
            ri[(tm4 + i) * 16 + tkq] = bk[i];
        }
    }
    __syncthreads();
    if (t < 64) {
        float bs = 3.4e38f; int bi = 0x7fffffff;
#pragma unroll
        for (int j = 0; j < 16; ++j) {
            const float s = rs[t * 16 + j];
            const int k = ri[t * 16 + j];
            if (s < bs || (s == bs && k < bi)) { bs = s; bi = k; }
        }
        bidx[n0 + t] = bi;
    }
}

// ---------------- kernel 2: gather + write oup (NCHW) + loss partials ----------------
__global__ __launch_bounds__(256) void gather_kernel(
    const float* __restrict__ x, const float* __restrict__ emb,
    const int* __restrict__ bidx, float* __restrict__ oup,
    float* __restrict__ partial)
{
    __shared__ int sidx[64];
    __shared__ float red[256];
    const int t = threadIdx.x;
    const int n0 = blockIdx.x * 64;
    const int b = n0 >> 10;
    const int pixbase = n0 & (N_PIX - 1);
    if (t < 64) sidx[t] = bidx[n0 + t];
    __syncthreads();
    const int pl = t & 63;    // pixel within tile (contiguous lanes -> coalesced x/oup)
    const int w = t >> 6;     // c quadrant
    const int k = sidx[pl];
    const float* xb = x + (size_t)b * CCH * N_PIX + pixbase + pl;
    float* ob = oup + (size_t)b * CCH * N_PIX + pixbase + pl;
    const float* ek = emb + (size_t)k * CCH + w * 64;
    float lsum = 0.f;
#pragma unroll 4
    for (int cc = 0; cc < 16; ++cc) {
        const float4 e4 = *(const float4*)(ek + cc * 4);
        const float er[4] = {e4.x, e4.y, e4.z, e4.w};
#pragma unroll
        for (int j = 0; j < 4; ++j) {
            const size_t off = (size_t)(w * 64 + cc * 4 + j) * N_PIX;
            const float xv = xb[off];
            ob[off] = er[j];
            const float d = xv - er[j];
            lsum = fmaf(d, d, lsum);
        }
    }
    red[t] = lsum;
    __syncthreads();
#pragma unroll
    for (int s = 128; s > 0; s >>= 1) {
        if (t < s) red[t] += red[t + s];
        __syncthreads();
    }
    if (t == 0) partial[blockIdx.x] = red[0];
}

// ---------------- kernel 3: finalize losses ----------------
__global__ __launch_bounds__(256) void finalize_kernel(const float* __restrict__ partial,
                                                       float* __restrict__ out_losses) {
    __shared__ float red[256];
    const int t = threadIdx.x;
    red[t] = partial[t] + partial[t + 256];
    __syncthreads();
    for (int s = 128; s > 0; s >>= 1) {
        if (t < s) red[t] += red[t + s];
        __syncthreads();
    }
    if (t == 0) {
        const float loss = red[0] * (1.0f / 8388608.0f);
        out_losses[0] = loss;   // dictionary_loss
        out_losses[1] = loss;   // commitment_loss (numerically identical)
    }
}

extern "C" void kernel_launch(void* const* d_in, const int* in_sizes, int n_in,
                              void* d_out, int out_size, void* d_ws, size_t ws_size,
                              hipStream_t stream) {
    const float* x = (const float*)d_in[0];
    const float* emb = (const float*)d_in[1];
    float* out = (float*)d_out;

    // workspace layout
    float* esq = (float*)d_ws;                                  // 4096 f32 (16 KB)
    int* bidx = (int*)((char*)d_ws + 16384);                    // 32768 i32 (128 KB)
    float* partial = (float*)((char*)d_ws + 16384 + 131072);    // 512 f32 (2 KB)

    esq_kernel<<<KCODES / 4, 256, 0, stream>>>(emb, esq);
    argmin_kernel<<<NROWS / 64, 256, (256 * 64 + 32 * 64) * sizeof(float), stream>>>(x, emb, esq, bidx);
    gather_kernel<<<NROWS / 64, 256, 0, stream>>>(x, emb, bidx, out, partial);
    finalize_kernel<<<1, 256, 0, stream>>>(partial, out + 8388608);
}

// Round 2
// 921.173 us; speedup vs baseline: 1.1548x; 1.1548x over previous
//
#include <hip/hip_runtime.h>

#define N_PIX 1024      // 32*32 pixels per image
#define BATCH 32
#define CCH 256         // channels == code dim
#define KCODES 4096
#define NROWS 32768     // BATCH * N_PIX

#define BROWS 32        // rows per block (4 waves x 8 rows)
#define KTILE 512       // codes per k-tile (64 lanes x 8 codes)
#define DCH 16          // channels per LDS chunk

// ---------------- kernel 0: e_sq[k] = sum_c emb[k][c]^2 ----------------
__global__ __launch_bounds__(256) void esq_kernel(const float* __restrict__ emb,
                                                  float* __restrict__ esq) {
    const int t = threadIdx.x;
    const int w = t >> 6, l = t & 63;
    const int k = blockIdx.x * 4 + w;
    const float4 v = *(const float4*)(emb + (size_t)k * CCH + l * 4);
    float s = v.x * v.x + v.y * v.y + v.z * v.z + v.w * v.w;
#pragma unroll
    for (int off = 32; off > 0; off >>= 1) s += __shfl_down(s, off);
    if (l == 0) esq[k] = s;
}

// ---------------- kernel 1: fused distance + argmin ----------------
// score(n,k) = esq[k] - 2*dot(x_n, e_k)   (x_sq dropped: constant per row)
// Wave w owns rows w*8..w*8+7 (uniform across lanes -> broadcast LDS reads).
// Lane l owns codes {4l..4l+3} and {256+4l..256+4l+3} of each 512-code tile
// (stride-16B b128 reads -> bank-perfect). emb chunk staged transposed
// es[c][k] with pos = k ^ 4*(c>>2) swizzle (balances the transpose writes).
__global__ __launch_bounds__(256, 2) void argmin_kernel(
    const float* __restrict__ x, const float* __restrict__ emb,
    const float* __restrict__ esq, int* __restrict__ bidx)
{
    __shared__ float xs[CCH * BROWS];   // [c][r]  32 KB, resident whole kernel
    __shared__ float es[DCH * KTILE];   // [c_local][k swizzled] 32 KB per chunk

    const int t = threadIdx.x;
    const int w = t >> 6;       // wave id = row group
    const int l = t & 63;       // lane  = code group
    const int n0 = blockIdx.x * BROWS;
    const int b = n0 >> 10;
    const int pixbase = n0 & (N_PIX - 1);
    const float* xb = x + (size_t)b * CCH * N_PIX + pixbase;

    // stage x tile transposed: xs[c][r] = x[b][c][pixbase+r]
    {
        const int p4 = (t & 7) * 4;
        const int crow = t >> 3;
#pragma unroll
        for (int i = 0; i < 8; ++i) {
            const int c = i * 32 + crow;
            *(float4*)(xs + c * BROWS + p4) = *(const float4*)(xb + (size_t)c * N_PIX + p4);
        }
    }

    float best[8];
    int bk[8];
#pragma unroll
    for (int r = 0; r < 8; ++r) { best[r] = 3.4e38f; bk[r] = 0; }

    for (int kt = 0; kt < KCODES / KTILE; ++kt) {
        const int k0 = kt * KTILE;
        float acc[8][8];   // [row][code]
#pragma unroll
        for (int r = 0; r < 8; ++r)
#pragma unroll
            for (int j = 0; j < 8; ++j) acc[r][j] = 0.f;

        for (int dc = 0; dc < CCH / DCH; ++dc) {
            const int c0 = dc * DCH;
            __syncthreads();   // protect es from previous chunk's readers (also covers xs 1st iter)
            // stage es[c'][pos] = emb[k0+k][c0+c'], pos = k ^ (4*(c'>>2))
#pragma unroll
            for (int i = 0; i < 4; ++i) {
                const int idx = i * 256 + t;      // pair index 0..1023
                const int g = idx & 3;            // c-group (c' = 4g..4g+3)
                const int k = (idx >> 2) * 2;     // even code
                const float4 v0 = *(const float4*)(emb + (size_t)(k0 + k) * CCH + c0 + 4 * g);
                const float4 v1 = *(const float4*)(emb + (size_t)(k0 + k + 1) * CCH + c0 + 4 * g);
                const int pos = k ^ (4 * g);
                *(float2*)(es + (4 * g + 0) * KTILE + pos) = make_float2(v0.x, v1.x);
                *(float2*)(es + (4 * g + 1) * KTILE + pos) = make_float2(v0.y, v1.y);
                *(float2*)(es + (4 * g + 2) * KTILE + pos) = make_float2(v0.z, v1.z);
                *(float2*)(es + (4 * g + 3) * KTILE + pos) = make_float2(v0.w, v1.w);
            }
            __syncthreads();

#pragma unroll 4
            for (int c = 0; c < DCH; ++c) {
                const int sw = 4 * (c >> 2);
                const float4 ea = *(const float4*)(es + c * KTILE + ((4 * l) ^ sw));
                const float4 eb = *(const float4*)(es + c * KTILE + 256 + ((4 * l) ^ sw));
                const float4 xa = *(const float4*)(xs + (c0 + c) * BROWS + w * 8);      // uniform -> broadcast
                const float4 xc = *(const float4*)(xs + (c0 + c) * BROWS + w * 8 + 4);  // uniform -> broadcast
                const float xr[8] = {xa.x, xa.y, xa.z, xa.w, xc.x, xc.y, xc.z, xc.w};
                const float er[8] = {ea.x, ea.y, ea.z, ea.w, eb.x, eb.y, eb.z, eb.w};
#pragma unroll
                for (int r = 0; r < 8; ++r)
#pragma unroll
                    for (int j = 0; j < 8; ++j)
                        acc[r][j] = fmaf(xr[r], er[j], acc[r][j]);
            }
        }

        // fold: score = esq - 2*acc; running min, k ascending -> strict < keeps first
        const float4 q0 = *(const float4*)(esq + k0 + 4 * l);
        const float4 q1 = *(const float4*)(esq + k0 + 256 + 4 * l);
        const float qr[8] = {q0.x, q0.y, q0.z, q0.w, q1.x, q1.y, q1.z, q1.w};
#pragma unroll
        for (int r = 0; r < 8; ++r) {
#pragma unroll
            for (int j = 0; j < 8; ++j) {
                const float s = fmaf(-2.f, acc[r][j], qr[j]);
                const int kg = k0 + ((j < 4) ? (4 * l + j) : (256 + 4 * l + (j - 4)));
                if (s < best[r]) { best[r] = s; bk[r] = kg; }
            }
        }
    }

    // cross-lane merge per row (codes are disjoint across lanes)
#pragma unroll
    for (int r = 0; r < 8; ++r) {
        float bv = best[r]; int bi = bk[r];
#pragma unroll
        for (int off = 32; off > 0; off >>= 1) {
            const float ov = __shfl_xor(bv, off, 64);
            const int   oi = __shfl_xor(bi, off, 64);
            if (ov < bv || (ov == bv && oi < bi)) { bv = ov; bi = oi; }
        }
        if (l == 0) bidx[n0 + w * 8 + r] = bi;
    }
}

// ---------------- kernel 2: gather + write oup (NCHW) + loss partials ----------------
__global__ __launch_bounds__(256) void gather_kernel(
    const float* __restrict__ x, const float* __restrict__ emb,
    const int* __restrict__ bidx, float* __restrict__ oup,
    float* __restrict__ partial)
{
    __shared__ int sidx[64];
    __shared__ float red[256];
    const int t = threadIdx.x;
    const int n0 = blockIdx.x * 64;
    const int b = n0 >> 10;
    const int pixbase = n0 & (N_PIX - 1);
    if (t < 64) sidx[t] = bidx[n0 + t];
    __syncthreads();
    const int pl = t & 63;    // pixel within tile (contiguous lanes -> coalesced x/oup)
    const int w = t >> 6;     // c quadrant
    const int k = sidx[pl];
    const float* xbp = x + (size_t)b * CCH * N_PIX + pixbase + pl;
    float* ob = oup + (size_t)b * CCH * N_PIX + pixbase + pl;
    const float* ek = emb + (size_t)k * CCH + w * 64;
    float lsum = 0.f;
#pragma unroll 4
    for (int cc = 0; cc < 16; ++cc) {
        const float4 e4 = *(const float4*)(ek + cc * 4);
        const float er[4] = {e4.x, e4.y, e4.z, e4.w};
#pragma unroll
        for (int j = 0; j < 4; ++j) {
            const size_t off = (size_t)(w * 64 + cc * 4 + j) * N_PIX;
            const float xv = xbp[off];
            ob[off] = er[j];
            const float d = xv - er[j];
            lsum = fmaf(d, d, lsum);
        }
    }
    red[t] = lsum;
    __syncthreads();
#pragma unroll
    for (int s = 128; s > 0; s >>= 1) {
        if (t < s) red[t] += red[t + s];
        __syncthreads();
    }
    if (t == 0) partial[blockIdx.x] = red[0];
}

// ---------------- kernel 3: finalize losses ----------------
__global__ __launch_bounds__(256) void finalize_kernel(const float* __restrict__ partial,
                                                       float* __restrict__ out_losses) {
    __shared__ float red[256];
    const int t = threadIdx.x;
    red[t] = partial[t] + partial[t + 256];
    __syncthreads();
    for (int s = 128; s > 0; s >>= 1) {
        if (t < s) red[t] += red[t + s];
        __syncthreads();
    }
    if (t == 0) {
        const float loss = red[0] * (1.0f / 8388608.0f);
        out_losses[0] = loss;   // dictionary_loss
        out_losses[1] = loss;   // commitment_loss (numerically identical)
    }
}

extern "C" void kernel_launch(void* const* d_in, const int* in_sizes, int n_in,
                              void* d_out, int out_size, void* d_ws, size_t ws_size,
                              hipStream_t stream) {
    const float* x = (const float*)d_in[0];
    const float* emb = (const float*)d_in[1];
    float* out = (float*)d_out;

    // workspace layout
    float* esq = (float*)d_ws;                                  // 4096 f32 (16 KB)
    int* bidx = (int*)((char*)d_ws + 16384);                    // 32768 i32 (128 KB)
    float* partial = (float*)((char*)d_ws + 16384 + 131072);    // 512 f32 (2 KB)

    esq_kernel<<<KCODES / 4, 256, 0, stream>>>(emb, esq);
    argmin_kernel<<<NROWS / BROWS, 256, 0, stream>>>(x, emb, esq, bidx);
    gather_kernel<<<NROWS / 64, 256, 0, stream>>>(x, emb, bidx, out, partial);
    finalize_kernel<<<1, 256, 0, stream>>>(partial, out + 8388608);
}